// Round 1
// baseline (882.353 us; speedup 1.0000x reference)
//
#include <hip/hip_runtime.h>

// TransitionUp: segment mean-pool -> linear2+ReLU (tiny) -> broadcast ->
// [x, h[seg]] @ W1 + b1 -> BN(eval) -> ReLU.
//
// Folded math:
//   a[j]     = gamma[j] * rsqrt(run_var[j]+eps)
//   d[j]     = beta[j] - run_mean[j]*a[j]
//   W'[k][j] = W1[k][j] * a[j]                  (k in 0..63, the x-half)
//   bias'[b][j] = (h[b]@W1[64:] + b1)[j]*a[j] + d[j]
//   out[p][j] = relu( x[p]@W'[:,j] + bias'[seg(p)][j] )

#define MAXB 16   // problem has B=16 segments

typedef const __attribute__((address_space(1))) void* gas_ptr;
typedef __attribute__((address_space(3))) void* las_ptr;

__device__ __forceinline__ void async_lds16(const void* g, void* l) {
  // global -> LDS direct copy, 16B per lane; LDS dest is wave-uniform base,
  // HW writes lane i at base + i*16.
  __builtin_amdgcn_global_load_lds((gas_ptr)g, (las_ptr)l, 16, 0, 0);
}

// ---------------------------------------------------------------- kernel 1
// Per-segment column sums of x into gsums[B][64] (pre-zeroed via memset).
__global__ __launch_bounds__(256) void pool_kernel(
    const float* __restrict__ x, const int* __restrict__ o,
    float* __restrict__ gsums, int nB, int ptsPerBlock) {
  __shared__ float ssum[MAXB * 64];
  __shared__ int so_s[MAXB];
  const int tid = threadIdx.x;
  for (int i = tid; i < nB * 64; i += 256) ssum[i] = 0.f;
  if (tid < nB) so_s[tid] = o[tid];
  __syncthreads();

  const int c4 = (tid & 15) * 4;   // 4 consecutive columns per thread
  const int r  = tid >> 4;         // 16 rows covered per iteration
  int p = blockIdx.x * ptsPerBlock + r;
  const int iters = ptsPerBlock >> 4;

  int cs = 0;
  while (p >= so_s[cs]) cs++;      // o[nB-1] == npts guarantees termination
  int nxt = so_s[cs];

  float a0 = 0.f, a1 = 0.f, a2 = 0.f, a3 = 0.f;
  for (int i = 0; i < iters; ++i, p += 16) {
    if (p >= nxt) {                // crossed a segment boundary (rare)
      atomicAdd(&ssum[cs * 64 + c4 + 0], a0);
      atomicAdd(&ssum[cs * 64 + c4 + 1], a1);
      atomicAdd(&ssum[cs * 64 + c4 + 2], a2);
      atomicAdd(&ssum[cs * 64 + c4 + 3], a3);
      a0 = a1 = a2 = a3 = 0.f;
      do { cs++; } while (p >= so_s[cs]);
      nxt = so_s[cs];
    }
    float4 v = *(const float4*)(x + (size_t)p * 64 + c4);
    a0 += v.x; a1 += v.y; a2 += v.z; a3 += v.w;
  }
  atomicAdd(&ssum[cs * 64 + c4 + 0], a0);
  atomicAdd(&ssum[cs * 64 + c4 + 1], a1);
  atomicAdd(&ssum[cs * 64 + c4 + 2], a2);
  atomicAdd(&ssum[cs * 64 + c4 + 3], a3);
  __syncthreads();

  for (int i = tid; i < nB * 64; i += 256) {
    float v = ssum[i];
    if (v != 0.f) atomicAdd(&gsums[i], v);   // zero-skip: ~1-2 segs/block hot
  }
}

// ---------------------------------------------------------------- kernel 2
// Tiny: mean -> h = relu(mean@W2+b2) -> bias'[b][j], W'[k][j].
__global__ __launch_bounds__(256) void mid_kernel(
    const float* __restrict__ gsums, const int* __restrict__ o,
    const float* __restrict__ W2, const float* __restrict__ b2,
    const float* __restrict__ W1, const float* __restrict__ b1,
    const float* __restrict__ gamma, const float* __restrict__ beta,
    const float* __restrict__ rmean, const float* __restrict__ rvar,
    float* __restrict__ biasp, float* __restrict__ Wp, int nB) {
  __shared__ float smean[MAXB * 64];
  __shared__ float sh[MAXB * 64];
  const int tid = threadIdx.x;
  const int j = tid & 63;
  const int bq = tid >> 6;

  for (int i = tid; i < nB * 64; i += 256) {
    int b = i >> 6;
    int cnt = o[b] - (b ? o[b - 1] : 0);
    smean[i] = gsums[i] / (float)cnt;
  }
  __syncthreads();

  for (int b = bq; b < nB; b += 4) {
    float s = b2[j];
    for (int c = 0; c < 64; ++c) s = fmaf(smean[b * 64 + c], W2[c * 64 + j], s);
    sh[b * 64 + j] = fmaxf(s, 0.f);
  }
  __syncthreads();

  const float a = gamma[j] / sqrtf(rvar[j] + 1e-5f);
  const float d = beta[j] - rmean[j] * a;
  for (int b = bq; b < nB; b += 4) {
    float s = b1[j];
    for (int c = 0; c < 64; ++c) s = fmaf(sh[b * 64 + c], W1[(64 + c) * 64 + j], s);
    biasp[b * 64 + j] = s * a + d;
  }
  for (int k = bq; k < 64; k += 4) Wp[k * 64 + j] = W1[k * 64 + j] * a;
}

// ---------------------------------------------------------------- kernel 3
// out[p][j] = relu( x[p]@W'[:,j] + bias'[seg(p)][j] )
// lane = column j; W' column in 64 VGPRs; x tile broadcast from LDS.
#define FMA4(v, acc)                          \
  acc = fmaf(v.x, wcol[k + 0], acc);          \
  acc = fmaf(v.y, wcol[k + 1], acc);          \
  acc = fmaf(v.z, wcol[k + 2], acc);          \
  acc = fmaf(v.w, wcol[k + 3], acc);

__global__ __launch_bounds__(256) void main_kernel(
    const float* __restrict__ x, const int* __restrict__ o,
    const float* __restrict__ Wp, const float* __restrict__ biasp,
    float* __restrict__ out, int nB) {
  __shared__ float sx[128 * 64];     // 32 KB x tile (128 points)
  __shared__ float sb[MAXB * 64];    // 4 KB folded bias
  __shared__ int so_s[MAXB];

  const int tid  = threadIdx.x;
  const int lane = tid & 63;
  const int w    = tid >> 6;         // wave id (0..3)
  const int p0   = blockIdx.x * 128;

  for (int i = tid; i < nB * 64; i += 256) sb[i] = biasp[i];
  if (tid < nB) so_s[tid] = o[tid];

  // stage 32 KB of x: 8 x (global_load_lds 16B/lane) per wave
  {
    const char* gsrc = (const char*)(x + (size_t)p0 * 64);
    char* lbase = (char*)sx;
#pragma unroll
    for (int i = 0; i < 8; ++i) {
      int goff = i * 4096 + w * 1024 + lane * 16;
      int loff = i * 4096 + w * 1024;               // lane*16 added by HW
      async_lds16(gsrc + goff, lbase + loff);
    }
  }

  // W' column for this lane -> registers (reused for all 128 points)
  float wcol[64];
#pragma unroll
  for (int k = 0; k < 64; ++k) wcol[k] = Wp[k * 64 + lane];

  __syncthreads();   // drains global_load_lds (vmcnt) + LDS writes

  // wave handles local points [w*32, w*32+32), 4 at a time
  const int gbase = p0 + w * 32;
  int cs = 0;
  while (gbase >= so_s[cs]) cs++;    // o[nB-1]==N terminates
  int nxt = so_s[cs];
  float bv = sb[cs * 64 + lane];

  for (int g = 0; g < 8; ++g) {
    const int lp = w * 32 + g * 4;
    const float* r0 = &sx[(lp + 0) * 64];
    const float* r1 = &sx[(lp + 1) * 64];
    const float* r2 = &sx[(lp + 2) * 64];
    const float* r3 = &sx[(lp + 3) * 64];
    float a0 = 0.f, a1 = 0.f, a2 = 0.f, a3 = 0.f;
#pragma unroll
    for (int k = 0; k < 64; k += 4) {
      float4 v0 = *(const float4*)(r0 + k);   // broadcast ds_read_b128
      float4 v1 = *(const float4*)(r1 + k);
      float4 v2 = *(const float4*)(r2 + k);
      float4 v3 = *(const float4*)(r3 + k);
      FMA4(v0, a0)
      FMA4(v1, a1)
      FMA4(v2, a2)
      FMA4(v3, a3)
    }
    const int gp = p0 + lp;
#pragma unroll
    for (int u = 0; u < 4; ++u) {
      const int gpu = gp + u;
      if (gpu >= nxt) {                        // wave-uniform, rare
        do { cs++; } while (gpu >= so_s[cs]);
        nxt = so_s[cs];
        bv = sb[cs * 64 + lane];
      }
      float acc = (u == 0) ? a0 : (u == 1) ? a1 : (u == 2) ? a2 : a3;
      out[(size_t)gpu * 64 + lane] = fmaxf(acc + bv, 0.f);
    }
  }
}

// ---------------------------------------------------------------- launch
extern "C" void kernel_launch(void* const* d_in, const int* in_sizes, int n_in,
                              void* d_out, int out_size, void* d_ws, size_t ws_size,
                              hipStream_t stream) {
  const float* x     = (const float*)d_in[0];
  const int*   o     = (const int*)d_in[1];
  const float* W2    = (const float*)d_in[2];
  const float* b2    = (const float*)d_in[3];
  const float* W1    = (const float*)d_in[4];
  const float* b1    = (const float*)d_in[5];
  const float* gamma = (const float*)d_in[6];
  const float* beta  = (const float*)d_in[7];
  const float* rmean = (const float*)d_in[8];
  const float* rvar  = (const float*)d_in[9];
  float* out = (float*)d_out;

  const int npts = in_sizes[0] / 64;
  const int nB   = in_sizes[1];

  float* gsums = (float*)d_ws;              // [MAXB*64]
  float* biasp = gsums + MAXB * 64;         // [MAXB*64]
  float* Wp    = biasp + MAXB * 64;         // [64*64]

  hipMemsetAsync(gsums, 0, MAXB * 64 * sizeof(float), stream);

  const int blocks1 = 1024;                 // 1024 pts/block at N=1M
  pool_kernel<<<blocks1, 256, 0, stream>>>(x, o, gsums, nB, npts / blocks1);
  mid_kernel<<<1, 256, 0, stream>>>(gsums, o, W2, b2, W1, b1, gamma, beta,
                                    rmean, rvar, biasp, Wp, nB);
  main_kernel<<<npts / 128, 256, 0, stream>>>(x, o, Wp, biasp, out, nB);
}

// Round 2
// 524.686 us; speedup vs baseline: 1.6817x; 1.6817x over previous
//
#include <hip/hip_runtime.h>

// TransitionUp: segment mean-pool -> linear2+ReLU (tiny) -> broadcast ->
// [x, h[seg]] @ W1 + b1 -> BN(eval) -> ReLU.
//
// Folded math:
//   a[j]     = gamma[j] * rsqrt(run_var[j]+eps)
//   d[j]     = beta[j] - run_mean[j]*a[j]
//   W'[k][j] = W1[k][j] * a[j]                  (k in 0..63, the x-half)
//   bias'[b][j] = (h[b]@W1[64:] + b1)[j]*a[j] + d[j]
//   out[p][j] = relu( x[p]@W'[:,j] + bias'[seg(p)][j] )
//
// R2: main kernel is MFMA f16 16x16x32, NO LDS (R1 was LDS-broadcast-bound:
// 16 ds_read_b128/point/wave = 192 LDS-pipe cyc vs 128 FMA cyc -> 482us at
// 10% HBM). A fragments loaded straight from global fp32 -> cvt f16;
// B = W' (f16, transposed) pinned in 32 VGPRs; C layout col=lane&15,
// row=quad*4+reg (m89-verified).

#define MAXB 16

typedef _Float16 half8 __attribute__((ext_vector_type(8)));
typedef float float4v __attribute__((ext_vector_type(4)));

// ---------------------------------------------------------------- kernel 1
// Per-segment column sums of x into gsums[B][64] (pre-zeroed via memset).
// Fast path: block's whole point range in one segment -> branch-free MLP loop.
__global__ __launch_bounds__(256) void pool_kernel(
    const float* __restrict__ x, const int* __restrict__ o,
    float* __restrict__ gsums, int nB, int ptsPerBlock) {
  __shared__ int so_s[MAXB];
  __shared__ float red[16 * 64];      // fast-path reduction scratch
  __shared__ float ssum2[MAXB * 64];  // slow-path bins
  const int tid = threadIdx.x;
  if (tid < nB) so_s[tid] = o[tid];
  __syncthreads();

  const int c4 = (tid & 15) * 4;  // 4 consecutive columns per thread
  const int r  = tid >> 4;        // 16 rows per 256 threads
  const int p0 = blockIdx.x * ptsPerBlock;
  const int iters = ptsPerBlock >> 4;

  int sFirst = 0;
  while (p0 >= so_s[sFirst]) sFirst++;
  int sLast = sFirst;
  while (p0 + ptsPerBlock - 1 >= so_s[sLast]) sLast++;

  if (sFirst == sLast) {  // block-uniform branch
    float a0 = 0.f, a1 = 0.f, a2 = 0.f, a3 = 0.f;
    const float* xp = x + (size_t)(p0 + r) * 64 + c4;
#pragma unroll 4
    for (int i = 0; i < iters; ++i) {
      float4 v = *(const float4*)(xp + (size_t)i * 1024);
      a0 += v.x; a1 += v.y; a2 += v.z; a3 += v.w;
    }
    float4 t = {a0, a1, a2, a3};
    *(float4*)&red[r * 64 + c4] = t;
    __syncthreads();
    if (tid < 64) {
      float s = 0.f;
#pragma unroll
      for (int rr = 0; rr < 16; ++rr) s += red[rr * 64 + tid];
      atomicAdd(&gsums[sFirst * 64 + tid], s);
    }
  } else {  // boundary block (rare): per-point binning
    for (int i = tid; i < nB * 64; i += 256) ssum2[i] = 0.f;
    __syncthreads();
    for (int i = 0; i < iters; ++i) {
      int p = p0 + i * 16 + r;
      int s = 0;
      while (p >= so_s[s]) s++;
      float4 v = *(const float4*)(x + (size_t)p * 64 + c4);
      atomicAdd(&ssum2[s * 64 + c4 + 0], v.x);
      atomicAdd(&ssum2[s * 64 + c4 + 1], v.y);
      atomicAdd(&ssum2[s * 64 + c4 + 2], v.z);
      atomicAdd(&ssum2[s * 64 + c4 + 3], v.w);
    }
    __syncthreads();
    for (int i = tid; i < nB * 64; i += 256) {
      float v = ssum2[i];
      if (v != 0.f) atomicAdd(&gsums[i], v);
    }
  }
}

// ---------------------------------------------------------------- kernel 2
// mean -> h = relu(mean@W2+b2) -> bias'[b][j]; WpT[j][k] = f16(W1[k][j]*a[j]).
__global__ __launch_bounds__(256) void mid_kernel(
    const float* __restrict__ gsums, const int* __restrict__ o,
    const float* __restrict__ W2, const float* __restrict__ b2,
    const float* __restrict__ W1, const float* __restrict__ b1,
    const float* __restrict__ gamma, const float* __restrict__ beta,
    const float* __restrict__ rmean, const float* __restrict__ rvar,
    float* __restrict__ biasp, _Float16* __restrict__ WpT, int nB) {
  __shared__ float smean[MAXB * 64];
  __shared__ float sh[MAXB * 64];
  const int tid = threadIdx.x;
  const int j = tid & 63;
  const int bq = tid >> 6;

  for (int i = tid; i < nB * 64; i += 256) {
    int b = i >> 6;
    int cnt = o[b] - (b ? o[b - 1] : 0);
    smean[i] = gsums[i] / (float)cnt;
  }
  __syncthreads();

  for (int b = bq; b < nB; b += 4) {
    float p0 = 0.f, p1 = 0.f, p2 = 0.f, p3 = 0.f;  // 4 chains for ILP
#pragma unroll
    for (int c = 0; c < 64; c += 4) {
      p0 = fmaf(smean[b * 64 + c + 0], W2[(c + 0) * 64 + j], p0);
      p1 = fmaf(smean[b * 64 + c + 1], W2[(c + 1) * 64 + j], p1);
      p2 = fmaf(smean[b * 64 + c + 2], W2[(c + 2) * 64 + j], p2);
      p3 = fmaf(smean[b * 64 + c + 3], W2[(c + 3) * 64 + j], p3);
    }
    sh[b * 64 + j] = fmaxf(((p0 + p1) + (p2 + p3)) + b2[j], 0.f);
  }
  __syncthreads();

  const float a = gamma[j] * rsqrtf(rvar[j] + 1e-5f);
  const float d = beta[j] - rmean[j] * a;
  for (int b = bq; b < nB; b += 4) {
    float p0 = 0.f, p1 = 0.f, p2 = 0.f, p3 = 0.f;
#pragma unroll
    for (int c = 0; c < 64; c += 4) {
      p0 = fmaf(sh[b * 64 + c + 0], W1[(64 + c + 0) * 64 + j], p0);
      p1 = fmaf(sh[b * 64 + c + 1], W1[(64 + c + 1) * 64 + j], p1);
      p2 = fmaf(sh[b * 64 + c + 2], W1[(64 + c + 2) * 64 + j], p2);
      p3 = fmaf(sh[b * 64 + c + 3], W1[(64 + c + 3) * 64 + j], p3);
    }
    biasp[b * 64 + j] = (((p0 + p1) + (p2 + p3)) + b1[j]) * a + d;
  }
  for (int k = bq * 16; k < bq * 16 + 16; ++k)
    WpT[j * 64 + k] = (_Float16)(W1[k * 64 + j] * a);
}

// ---------------------------------------------------------------- kernel 3
// Each wave: 8 row-tiles of 16 points, 4 col-tiles of 16. No LDS, no barrier.
// A frag (m89 layout): lane holds A[m=lane&15][k=quad*8+j], fp32->f16 cvt.
// B frag: lane holds B[k=quad*8+j][n=lane&15] from WpT[n][k] (contiguous).
__global__ __launch_bounds__(256) void main_kernel(
    const float* __restrict__ x, const int* __restrict__ o,
    const _Float16* __restrict__ WpT, const float* __restrict__ biasp,
    float* __restrict__ out, int nB) {
  const int lane = threadIdx.x & 63;
  const int m = lane & 15;
  const int quad = lane >> 4;
  const int rows0 = (blockIdx.x * 4 + (threadIdx.x >> 6)) * 128;

  // B = W' pinned in registers: 4 col-tiles x 2 K-halves x 8 f16
  half8 bfrag[4][2];
#pragma unroll
  for (int t = 0; t < 4; ++t)
#pragma unroll
    for (int h = 0; h < 2; ++h)
      bfrag[t][h] = *(const half8*)(WpT + (t * 16 + m) * 64 + h * 32 + quad * 8);

  // lane m holds o[m] for ballot-based segment lookup
  const int ov = (m < nB) ? o[m] : 0x7fffffff;

  float4 f0, f1, f2, f3;  // fp32 staging for one 16x64 A-tile (this lane: 16 floats)
  {
    const float* p = x + (size_t)(rows0 + m) * 64 + quad * 8;
    f0 = *(const float4*)(p + 0);
    f1 = *(const float4*)(p + 4);
    f2 = *(const float4*)(p + 32);
    f3 = *(const float4*)(p + 36);
  }

  for (int i = 0; i < 8; ++i) {
    const int row0 = rows0 + i * 16;
    // cvt staging -> f16 fragments (k 0..31 and 32..63)
    half8 a0, a1;
    a0[0] = (_Float16)f0.x; a0[1] = (_Float16)f0.y;
    a0[2] = (_Float16)f0.z; a0[3] = (_Float16)f0.w;
    a0[4] = (_Float16)f1.x; a0[5] = (_Float16)f1.y;
    a0[6] = (_Float16)f1.z; a0[7] = (_Float16)f1.w;
    a1[0] = (_Float16)f2.x; a1[1] = (_Float16)f2.y;
    a1[2] = (_Float16)f2.z; a1[3] = (_Float16)f2.w;
    a1[4] = (_Float16)f3.x; a1[5] = (_Float16)f3.y;
    a1[6] = (_Float16)f3.z; a1[7] = (_Float16)f3.w;

    if (i < 7) {  // prefetch next tile while MFMA+stores run
      const float* p = x + (size_t)(row0 + 16 + m) * 64 + quad * 8;
      f0 = *(const float4*)(p + 0);
      f1 = *(const float4*)(p + 4);
      f2 = *(const float4*)(p + 32);
      f3 = *(const float4*)(p + 36);
    }

    // segment of this 16-row tile via ballot popcount (o in lanes 0..15)
    const int s0 = (int)__popcll(__ballot(row0 >= ov) & 0xFFFFull);
    const int s1 = (int)__popcll(__ballot(row0 + 15 >= ov) & 0xFFFFull);

    if (s0 == s1) {  // tile entirely in one segment (common)
      const float* bp = biasp + s0 * 64 + m;
#pragma unroll
      for (int t = 0; t < 4; ++t) {
        float4v c = {0.f, 0.f, 0.f, 0.f};
        c = __builtin_amdgcn_mfma_f32_16x16x32_f16(a0, bfrag[t][0], c, 0, 0, 0);
        c = __builtin_amdgcn_mfma_f32_16x16x32_f16(a1, bfrag[t][1], c, 0, 0, 0);
        const float bv = bp[t * 16];
        float* op = out + (size_t)(row0 + quad * 4) * 64 + t * 16 + m;
#pragma unroll
        for (int rg = 0; rg < 4; ++rg)
          op[(size_t)rg * 64] = fmaxf(c[rg] + bv, 0.f);
      }
    } else {  // boundary tile (rare): per-row segment scan
#pragma unroll
      for (int t = 0; t < 4; ++t) {
        float4v c = {0.f, 0.f, 0.f, 0.f};
        c = __builtin_amdgcn_mfma_f32_16x16x32_f16(a0, bfrag[t][0], c, 0, 0, 0);
        c = __builtin_amdgcn_mfma_f32_16x16x32_f16(a1, bfrag[t][1], c, 0, 0, 0);
#pragma unroll
        for (int rg = 0; rg < 4; ++rg) {
          const int row = row0 + quad * 4 + rg;
          int s = 0;
          for (int q2 = 0; q2 < nB; ++q2) s += (row >= o[q2]) ? 1 : 0;
          const float bv = biasp[s * 64 + t * 16 + m];
          out[(size_t)row * 64 + t * 16 + m] = fmaxf(c[rg] + bv, 0.f);
        }
      }
    }
  }
}

// ---------------------------------------------------------------- launch
extern "C" void kernel_launch(void* const* d_in, const int* in_sizes, int n_in,
                              void* d_out, int out_size, void* d_ws, size_t ws_size,
                              hipStream_t stream) {
  const float* x     = (const float*)d_in[0];
  const int*   o     = (const int*)d_in[1];
  const float* W2    = (const float*)d_in[2];
  const float* b2    = (const float*)d_in[3];
  const float* W1    = (const float*)d_in[4];
  const float* b1    = (const float*)d_in[5];
  const float* gamma = (const float*)d_in[6];
  const float* beta  = (const float*)d_in[7];
  const float* rmean = (const float*)d_in[8];
  const float* rvar  = (const float*)d_in[9];
  float* out = (float*)d_out;

  const int npts = in_sizes[0] / 64;
  const int nB   = in_sizes[1];

  float*    gsums = (float*)d_ws;                 // [16*64] f32
  float*    biasp = gsums + MAXB * 64;            // [16*64] f32
  _Float16* WpT   = (_Float16*)(biasp + MAXB * 64);  // [64*64] f16 (16B-aligned)

  hipMemsetAsync(gsums, 0, MAXB * 64 * sizeof(float), stream);

  const int blocks1 = 2048;                       // 512 pts/block at N=1M
  pool_kernel<<<blocks1, 256, 0, stream>>>(x, o, gsums, nB, npts / blocks1);
  mid_kernel<<<1, 256, 0, stream>>>(gsums, o, W2, b2, W1, b1, gamma, beta,
                                    rmean, rvar, biasp, WpT, nB);
  main_kernel<<<npts / 512, 256, 0, stream>>>(x, o, WpT, biasp, out, nB);
}